// Round 1
// baseline (849.808 us; speedup 1.0000x reference)
//
#include <hip/hip_runtime.h>
#include <hip/hip_bf16.h>
#include <cstdint>

typedef unsigned short u16;
typedef unsigned int u32;
typedef __attribute__((ext_vector_type(4))) int i32x4;
typedef __attribute__((ext_vector_type(4))) float f32x4;
typedef __attribute__((ext_vector_type(8))) unsigned short u16x8;

// ---------- helpers ----------
__device__ __forceinline__ u16 f2bf(float f) {
  u32 u = __builtin_bit_cast(u32, f);
  u += 0x7FFFu + ((u >> 16) & 1u);          // RNE
  return (u16)(u >> 16);
}

__device__ __forceinline__ f32x4 mfma16(i32x4 a, i32x4 b, f32x4 c) {
  asm("v_mfma_f32_16x16x32_bf16 %0, %1, %2, %0" : "+v"(c) : "v"(a), "v"(b));
  return c;
}

__device__ __forceinline__ void gload_lds16(const void* g, void* l) {
  __builtin_amdgcn_global_load_lds((__attribute__((address_space(1))) void*)g,
                                   (__attribute__((address_space(3))) void*)l,
                                   16, 0, 0);
}

// ---------- fp32 -> bf16 convert ----------
__global__ __launch_bounds__(256) void cvt_bf16_kernel(const float* __restrict__ s,
                                                       u16* __restrict__ d, int n) {
  int i = blockIdx.x * 256 + threadIdx.x;
  if (i < n) d[i] = f2bf(s[i]);
}

// ---------- bias table: bias_t[h][n][m] = rpb[rp_index[n*144+m]][h] ----------
__global__ __launch_bounds__(256) void bias_table_kernel(const float* __restrict__ rpb,
                                                         const int* __restrict__ rp_index,
                                                         float* __restrict__ bias_t) {
  int i = blockIdx.x * 256 + threadIdx.x;     // < 16*144*144 = 331776
  if (i < 331776) {
    int h = i / 20736;
    int r = i - h * 20736;                    // n*144+m
    bias_t[i] = rpb[rp_index[r] * 16 + h];
  }
}

// ---------- LayerNorm over C=512, out bf16; 4 tokens/block, 1 wave/token ----------
__global__ __launch_bounds__(256) void ln_kernel(const float* __restrict__ x,
                                                 const float* __restrict__ w,
                                                 const float* __restrict__ b,
                                                 u16* __restrict__ out) {
  int lane = threadIdx.x & 63;
  size_t token = (size_t)blockIdx.x * 4 + (threadIdx.x >> 6);
  const float* row = x + token * 512;
  float4 v0 = *(const float4*)(row + lane * 8);
  float4 v1 = *(const float4*)(row + lane * 8 + 4);
  float s  = v0.x + v0.y + v0.z + v0.w + v1.x + v1.y + v1.z + v1.w;
  float ss = v0.x*v0.x + v0.y*v0.y + v0.z*v0.z + v0.w*v0.w
           + v1.x*v1.x + v1.y*v1.y + v1.z*v1.z + v1.w*v1.w;
#pragma unroll
  for (int m = 32; m >= 1; m >>= 1) { s += __shfl_xor(s, m); ss += __shfl_xor(ss, m); }
  float mu  = s * (1.f / 512.f);
  float var = ss * (1.f / 512.f) - mu * mu;
  float rstd = rsqrtf(var + 1e-5f);
  float4 w0 = *(const float4*)(w + lane * 8);
  float4 w1 = *(const float4*)(w + lane * 8 + 4);
  float4 b0 = *(const float4*)(b + lane * 8);
  float4 b1 = *(const float4*)(b + lane * 8 + 4);
  u16x8 o;
  o[0] = f2bf((v0.x - mu) * rstd * w0.x + b0.x);
  o[1] = f2bf((v0.y - mu) * rstd * w0.y + b0.y);
  o[2] = f2bf((v0.z - mu) * rstd * w0.z + b0.z);
  o[3] = f2bf((v0.w - mu) * rstd * w0.w + b0.w);
  o[4] = f2bf((v1.x - mu) * rstd * w1.x + b1.x);
  o[5] = f2bf((v1.y - mu) * rstd * w1.y + b1.y);
  o[6] = f2bf((v1.z - mu) * rstd * w1.z + b1.z);
  o[7] = f2bf((v1.w - mu) * rstd * w1.w + b1.w);
  *(u16x8*)(out + token * 512 + lane * 8) = o;
}

// ---------- GEMM: C[M,N] = A[M,K](bf16) * B[N,K]^T(bf16) + bias ----------
// EPI 0: bf16 out;  1: gelu->bf16 out;  2: fp32 out = res + acc + bias
template <int EPI>
__global__ __launch_bounds__(256) void gemm_bt(const u16* __restrict__ A,
                                               const u16* __restrict__ B,
                                               const float* __restrict__ bias,
                                               const float* __restrict__ res,
                                               void* __restrict__ Cout,
                                               int M, int N, int K) {
  __shared__ __align__(16) u16 As[128 * 32];
  __shared__ __align__(16) u16 Bs[128 * 32];
  int tid = threadIdx.x, lane = tid & 63, wid = tid >> 6;
  int m0 = blockIdx.x * 128, n0 = blockIdx.y * 128;
  int wm = (wid >> 1) * 64, wn = (wid & 1) * 64;
  const u16* Ab = A + (size_t)m0 * K;
  const u16* Bb = B + (size_t)n0 * K;
  f32x4 acc[4][4] = {};
  for (int kt = 0; kt < K; kt += 32) {
#pragma unroll
    for (int i = 0; i < 2; ++i) {
      int id = i * 256 + tid;               // 0..511
      int row = id >> 2, c8 = (id & 3) * 8; // row 0..127, col chunk
      gload_lds16(Ab + (size_t)row * K + kt + c8, &As[id * 8]);
      gload_lds16(Bb + (size_t)row * K + kt + c8, &Bs[id * 8]);
    }
    __syncthreads();
    i32x4 af[4], bfr[4];
#pragma unroll
    for (int i = 0; i < 4; ++i) {
      af[i]  = *(const i32x4*)&As[(wm + i * 16 + (lane & 15)) * 32 + (lane >> 4) * 8];
      bfr[i] = *(const i32x4*)&Bs[(wn + i * 16 + (lane & 15)) * 32 + (lane >> 4) * 8];
    }
#pragma unroll
    for (int i = 0; i < 4; ++i)
#pragma unroll
      for (int j = 0; j < 4; ++j) acc[i][j] = mfma16(af[i], bfr[j], acc[i][j]);
    __syncthreads();
  }
  int cl = lane & 15;
  int rb = (lane >> 4) * 4;
#pragma unroll
  for (int j = 0; j < 4; ++j) {
    int nn = n0 + wn + j * 16 + cl;
    float bn = bias[nn];
#pragma unroll
    for (int i = 0; i < 4; ++i) {
      int mm = m0 + wm + i * 16 + rb;
#pragma unroll
      for (int r = 0; r < 4; ++r) {
        float v = acc[i][j][r] + bn;
        size_t off = (size_t)(mm + r) * N + nn;
        if constexpr (EPI == 1) v = 0.5f * v * (1.f + erff(v * 0.70710678118654752f));
        if constexpr (EPI == 2) ((float*)Cout)[off] = res[off] + v;
        else ((u16*)Cout)[off] = f2bf(v);
      }
    }
  }
}

// ---------- window attention: one block per (window, head) ----------
// qkv: [T][1536] bf16 (q|k|v, each head h at h*32). out: [T][512] bf16.
__global__ __launch_bounds__(256) void attn_kernel(const u16* __restrict__ qkv,
                                                   const float* __restrict__ bias_t,
                                                   u16* __restrict__ attn_out) {
  __shared__ __align__(16) u16 vT[32][160];       // v transposed, K padded to 160
  __shared__ __align__(16) u16 Plds[4][16][160];  // per-wave P strip
  __shared__ u32 tok[144];
  int tid = threadIdx.x, lane = tid & 63, wid = tid >> 6;
  int blk = blockIdx.x;
  int h = blk & 15, w = blk >> 4;
  int zi = w >> 6, hi = (w >> 3) & 7, wi = w & 7;

  if (tid < 144) {
    int a = tid / 72, rem = tid - a * 72;
    int b = rem / 12, c = rem - b * 12;
    tok[tid] = ((u32)(zi * 2 + a) * 48 + hi * 6 + b) * 96 + wi * 12 + c;
  }
  for (int e = tid; e < 512; e += 256) vT[e >> 4][144 + (e & 15)] = 0;  // zero K-pad
  __syncthreads();  // tok ready

  // stage V transposed: [d][n]
  for (int idx = tid; idx < 576; idx += 256) {
    int n = idx >> 2, d8 = (idx & 3) * 8;
    u16x8 v = *(const u16x8*)(qkv + (size_t)tok[n] * 1536 + 1024 + h * 32 + d8);
#pragma unroll
    for (int j = 0; j < 8; ++j) vT[d8 + j][n] = v[j];
  }
  // zero this wave's P pad columns (144..159)
#pragma unroll
  for (int rr = 0; rr < 4; ++rr) Plds[wid][(lane >> 4) * 4 + rr][144 + (lane & 15)] = 0;
  __syncthreads();  // vT ready

  const float scale = 0.17677669529663687f;  // 1/sqrt(32)
  for (int rt = wid; rt < 9; rt += 4) {
    int qrow = rt * 16 + (lane & 15);
    i32x4 aq = *(const i32x4*)(qkv + (size_t)tok[qrow] * 1536 + h * 32 + (lane >> 4) * 8);
    f32x4 s[9];
#pragma unroll
    for (int ct = 0; ct < 9; ++ct) {
      int krow = ct * 16 + (lane & 15);
      i32x4 bk = *(const i32x4*)(qkv + (size_t)tok[krow] * 1536 + 512 + h * 32 + (lane >> 4) * 8);
      f32x4 z = {0.f, 0.f, 0.f, 0.f};
      s[ct] = mfma16(aq, bk, z);
    }
    int rowb = rt * 16 + (lane >> 4) * 4;
#pragma unroll
    for (int ct = 0; ct < 9; ++ct)
#pragma unroll
      for (int rr = 0; rr < 4; ++rr)
        s[ct][rr] = s[ct][rr] * scale +
                    bias_t[((size_t)h * 144 + rowb + rr) * 144 + ct * 16 + (lane & 15)];
    float mx[4], sm[4], inv[4];
#pragma unroll
    for (int rr = 0; rr < 4; ++rr) {
      float m = s[0][rr];
#pragma unroll
      for (int ct = 1; ct < 9; ++ct) m = fmaxf(m, s[ct][rr]);
#pragma unroll
      for (int msk = 8; msk >= 1; msk >>= 1) m = fmaxf(m, __shfl_xor(m, msk));
      mx[rr] = m;
      sm[rr] = 0.f;
    }
#pragma unroll
    for (int ct = 0; ct < 9; ++ct)
#pragma unroll
      for (int rr = 0; rr < 4; ++rr) {
        float p = __expf(s[ct][rr] - mx[rr]);
        s[ct][rr] = p;
        sm[rr] += p;
      }
#pragma unroll
    for (int rr = 0; rr < 4; ++rr) {
#pragma unroll
      for (int msk = 8; msk >= 1; msk >>= 1) sm[rr] += __shfl_xor(sm[rr], msk);
      inv[rr] = 1.f / sm[rr];
    }
#pragma unroll
    for (int ct = 0; ct < 9; ++ct)
#pragma unroll
      for (int rr = 0; rr < 4; ++rr)
        Plds[wid][(lane >> 4) * 4 + rr][ct * 16 + (lane & 15)] = f2bf(s[ct][rr] * inv[rr]);
    // PV: O(16x32) = P(16x160) x v(160x32)
#pragma unroll
    for (int dt = 0; dt < 2; ++dt) {
      f32x4 o = {0.f, 0.f, 0.f, 0.f};
#pragma unroll
      for (int ct = 0; ct < 5; ++ct) {
        i32x4 ap = *(const i32x4*)&Plds[wid][lane & 15][ct * 32 + (lane >> 4) * 8];
        i32x4 bv = *(const i32x4*)&vT[dt * 16 + (lane & 15)][ct * 32 + (lane >> 4) * 8];
        o = mfma16(ap, bv, o);
      }
#pragma unroll
      for (int rr = 0; rr < 4; ++rr)
        attn_out[(size_t)tok[rowb + rr] * 512 + h * 32 + dt * 16 + (lane & 15)] = f2bf(o[rr]);
    }
  }
}

// ---------- launch ----------
extern "C" void kernel_launch(void* const* d_in, const int* in_sizes, int n_in,
                              void* d_out, int out_size, void* d_ws, size_t ws_size,
                              hipStream_t stream) {
  const float* x      = (const float*)d_in[0];
  const float* ln1_w  = (const float*)d_in[1];
  const float* ln1_b  = (const float*)d_in[2];
  const float* qkv_w  = (const float*)d_in[3];
  const float* qkv_b  = (const float*)d_in[4];
  const float* rpb    = (const float*)d_in[5];
  const float* proj_w = (const float*)d_in[6];
  const float* proj_b = (const float*)d_in[7];
  const float* ln2_w  = (const float*)d_in[8];
  const float* ln2_b  = (const float*)d_in[9];
  const float* fc1_w  = (const float*)d_in[10];
  const float* fc1_b  = (const float*)d_in[11];
  const float* fc2_w  = (const float*)d_in[12];
  const float* fc2_b  = (const float*)d_in[13];
  const int*   rp_idx = (const int*)d_in[14];
  float* out = (float*)d_out;
  char* ws = (char*)d_ws;

  const int T = 36864;  // 8*48*96 tokens
  // workspace layout (bytes)
  u16*   w_qkv  = (u16*)(ws + 0);                    // 1536*512*2   = 1572864
  u16*   w_proj = (u16*)(ws + 1572864);              // 512*512*2    = 524288
  u16*   w_fc1  = (u16*)(ws + 2097152);              // 2048*512*2   = 2097152
  u16*   w_fc2  = (u16*)(ws + 4194304);              // 512*2048*2   = 2097152
  float* bias_t = (float*)(ws + 6291456);            // 16*144*144*4 = 1327104
  u16*   buf_ln  = (u16*)(ws + 7618560);             // T*512*2      = 37748736
  u16*   buf_qkv = (u16*)(ws + 45367296);            // T*2048*2     = 150994944 (qkv then h)
  u16*   buf_attn= (u16*)(ws + 196362240);           // T*512*2      = 37748736
  // total 234110976 bytes

  // weights -> bf16
  cvt_bf16_kernel<<<3072, 256, 0, stream>>>(qkv_w, w_qkv, 1536 * 512);
  cvt_bf16_kernel<<<1024, 256, 0, stream>>>(proj_w, w_proj, 512 * 512);
  cvt_bf16_kernel<<<4096, 256, 0, stream>>>(fc1_w, w_fc1, 2048 * 512);
  cvt_bf16_kernel<<<4096, 256, 0, stream>>>(fc2_w, w_fc2, 512 * 2048);
  bias_table_kernel<<<1296, 256, 0, stream>>>(rpb, rp_idx, bias_t);

  // LN1
  ln_kernel<<<T / 4, 256, 0, stream>>>(x, ln1_w, ln1_b, buf_ln);
  // QKV: [T,1536]
  gemm_bt<0><<<dim3(T / 128, 1536 / 128), 256, 0, stream>>>(
      buf_ln, w_qkv, qkv_b, nullptr, buf_qkv, T, 1536, 512);
  // attention
  attn_kernel<<<256 * 16, 256, 0, stream>>>(buf_qkv, bias_t, buf_attn);
  // proj + residual(x) -> d_out (fp32, holds x1)
  gemm_bt<2><<<dim3(T / 128, 512 / 128), 256, 0, stream>>>(
      buf_attn, w_proj, proj_b, x, out, T, 512, 512);
  // LN2 on x1
  ln_kernel<<<T / 4, 256, 0, stream>>>(out, ln2_w, ln2_b, buf_ln);
  // FC1 + gelu -> h (bf16, reuse buf_qkv)
  gemm_bt<1><<<dim3(T / 128, 2048 / 128), 256, 0, stream>>>(
      buf_ln, w_fc1, fc1_b, nullptr, buf_qkv, T, 2048, 512);
  // FC2 + residual(x1) -> d_out
  gemm_bt<2><<<dim3(T / 128, 512 / 128), 256, 0, stream>>>(
      buf_qkv, w_fc2, fc2_b, out, out, T, 512, 2048);
}

// Round 4
// 790.603 us; speedup vs baseline: 1.0749x; 1.0749x over previous
//
#include <hip/hip_runtime.h>
#include <hip/hip_bf16.h>
#include <cstdint>

typedef unsigned short u16;
typedef unsigned int u32;
typedef __attribute__((ext_vector_type(4))) int i32x4;
typedef __attribute__((ext_vector_type(4))) float f32x4;
typedef __attribute__((ext_vector_type(8))) unsigned short u16x8;

// ---------- helpers ----------
__device__ __forceinline__ u16 f2bf(float f) {
  u32 u = __builtin_bit_cast(u32, f);
  u += 0x7FFFu + ((u >> 16) & 1u);          // RNE
  return (u16)(u >> 16);
}

__device__ __forceinline__ f32x4 mfma16(i32x4 a, i32x4 b, f32x4 c) {
  asm("v_mfma_f32_16x16x32_bf16 %0, %1, %2, %0" : "+v"(c) : "v"(a), "v"(b));
  return c;
}

__device__ __forceinline__ void gload_lds16(const void* g, void* l) {
  __builtin_amdgcn_global_load_lds((__attribute__((address_space(1))) void*)g,
                                   (__attribute__((address_space(3))) void*)l,
                                   16, 0, 0);
}

// ---------- fp32 -> bf16 convert ----------
__global__ __launch_bounds__(256) void cvt_bf16_kernel(const float* __restrict__ s,
                                                       u16* __restrict__ d, int n) {
  int i = blockIdx.x * 256 + threadIdx.x;
  if (i < n) d[i] = f2bf(s[i]);
}

// ---------- bias table: bias_t[h][n][m] = rpb[rp_index[n*144+m]][h] ----------
__global__ __launch_bounds__(256) void bias_table_kernel(const float* __restrict__ rpb,
                                                         const int* __restrict__ rp_index,
                                                         float* __restrict__ bias_t) {
  int i = blockIdx.x * 256 + threadIdx.x;     // < 16*144*144 = 331776
  if (i < 331776) {
    int h = i / 20736;
    int r = i - h * 20736;                    // n*144+m
    bias_t[i] = rpb[rp_index[r] * 16 + h];
  }
}

// ---------- LayerNorm over C=512, out bf16; 4 tokens/block, 1 wave/token ----------
__global__ __launch_bounds__(256) void ln_kernel(const float* __restrict__ x,
                                                 const float* __restrict__ w,
                                                 const float* __restrict__ b,
                                                 u16* __restrict__ out) {
  int lane = threadIdx.x & 63;
  size_t token = (size_t)blockIdx.x * 4 + (threadIdx.x >> 6);
  const float* row = x + token * 512;
  float4 v0 = *(const float4*)(row + lane * 8);
  float4 v1 = *(const float4*)(row + lane * 8 + 4);
  float s  = v0.x + v0.y + v0.z + v0.w + v1.x + v1.y + v1.z + v1.w;
  float ss = v0.x*v0.x + v0.y*v0.y + v0.z*v0.z + v0.w*v0.w
           + v1.x*v1.x + v1.y*v1.y + v1.z*v1.z + v1.w*v1.w;
#pragma unroll
  for (int m = 32; m >= 1; m >>= 1) { s += __shfl_xor(s, m); ss += __shfl_xor(ss, m); }
  float mu  = s * (1.f / 512.f);
  float var = ss * (1.f / 512.f) - mu * mu;
  float rstd = rsqrtf(var + 1e-5f);
  float4 w0 = *(const float4*)(w + lane * 8);
  float4 w1 = *(const float4*)(w + lane * 8 + 4);
  float4 b0 = *(const float4*)(b + lane * 8);
  float4 b1 = *(const float4*)(b + lane * 8 + 4);
  u16x8 o;
  o[0] = f2bf((v0.x - mu) * rstd * w0.x + b0.x);
  o[1] = f2bf((v0.y - mu) * rstd * w0.y + b0.y);
  o[2] = f2bf((v0.z - mu) * rstd * w0.z + b0.z);
  o[3] = f2bf((v0.w - mu) * rstd * w0.w + b0.w);
  o[4] = f2bf((v1.x - mu) * rstd * w1.x + b1.x);
  o[5] = f2bf((v1.y - mu) * rstd * w1.y + b1.y);
  o[6] = f2bf((v1.z - mu) * rstd * w1.z + b1.z);
  o[7] = f2bf((v1.w - mu) * rstd * w1.w + b1.w);
  *(u16x8*)(out + token * 512 + lane * 8) = o;
}

// ---------- GEMM 256x256 tile, BK=32, 4-deep circular LDS pipeline ----------
// C[M,N] = A[M,K](bf16) * B[N,K]^T(bf16) + bias
// EPI 0: bf16 out;  1: gelu->bf16 out;  2: fp32 out = res + acc + bias
// 512 threads = 8 waves (2M x 4N); per-wave 128x64 output (acc[8][4] f32x4).
// LDS: 4 bufs x (A 16KB + B 16KB) = 128KB. Stage j+3 while computing j;
// counted vmcnt(12) keeps 3 tiles in flight across barriers (T4).
// T2 swizzle: 16B-slot ^= (row>>1)&3, applied on the global SOURCE of
// global_load_lds (linear LDS dest) and on the ds_read address (rule #21).
template <int EPI>
__global__ __launch_bounds__(512, 2) void gemm256(const u16* __restrict__ A,
                                                  const u16* __restrict__ B,
                                                  const float* __restrict__ bias,
                                                  const float* __restrict__ res,
                                                  void* __restrict__ Cout,
                                                  int M, int N, int K, int NBN) {
  __shared__ __align__(16) char smbuf[131072];
  int tid = threadIdx.x, l = tid & 63, wid = tid >> 6;
  int wm = wid >> 2, wn = wid & 3;
  // T1: bijective XCD swizzle (grids are multiples of 8)
  int nwg = gridDim.x;
  int wg = blockIdx.x;
  int swz = (wg & 7) * (nwg >> 3) + (wg >> 3);
  int bm = swz / NBN, bn = swz - bm * NBN;
  int m0 = bm * 256, n0 = bn * 256;
  // stage source (pre-swizzled global address, linear LDS dest)
  int srow = tid >> 2;                          // 0..127
  int sslot = (tid & 3) ^ ((tid >> 3) & 3);     // swizzled 16B slot
  const u16* gA = A + (size_t)(m0 + srow) * K + sslot * 8;
  const u16* gB = B + (size_t)(n0 + srow) * K + sslot * 8;
  size_t rK = (size_t)128 * K;
  int NT = K >> 5;
  // fragment read offsets (swizzled)
  int slot_r = (l >> 4) ^ ((l >> 1) & 3);
  int rbyte = (l & 15) * 64 + slot_r * 16;
  const char* Ab = smbuf + wm * 8192 + rbyte;
  const char* Bb = smbuf + 16384 + wn * 4096 + rbyte;
  f32x4 acc[8][4] = {};

#define STAGE(j) { \
    char* lb = smbuf + (((j) & 3) << 15) + tid * 16; \
    const u16* ga = gA + (size_t)(j) * 32; \
    const u16* gb = gB + (size_t)(j) * 32; \
    gload_lds16(ga,      lb); \
    gload_lds16(ga + rK, lb + 8192); \
    gload_lds16(gb,      lb + 16384); \
    gload_lds16(gb + rK, lb + 24576); }

  STAGE(0); STAGE(1); STAGE(2);
  for (int j = 0; j < NT; ++j) {
    if (j + 3 < NT) STAGE(j + 3);
    int ahead = NT - 1 - j;
    if (ahead >= 3)      asm volatile("s_waitcnt vmcnt(12)" ::: "memory");
    else if (ahead == 2) asm volatile("s_waitcnt vmcnt(8)" ::: "memory");
    else if (ahead == 1) asm volatile("s_waitcnt vmcnt(4)" ::: "memory");
    else                 asm volatile("s_waitcnt vmcnt(0)" ::: "memory");
    __builtin_amdgcn_s_barrier();
    int bo = (j & 3) << 15;
    i32x4 af[8], bfr[4];
#pragma unroll
    for (int m = 0; m < 8; ++m) af[m] = *(const i32x4*)(Ab + bo + m * 1024);
#pragma unroll
    for (int n = 0; n < 4; ++n) bfr[n] = *(const i32x4*)(Bb + bo + n * 1024);
    __builtin_amdgcn_s_setprio(1);
#pragma unroll
    for (int m = 0; m < 8; ++m)
#pragma unroll
      for (int n = 0; n < 4; ++n) acc[m][n] = mfma16(af[m], bfr[n], acc[m][n]);
    __builtin_amdgcn_s_setprio(0);
    asm volatile("s_waitcnt lgkmcnt(0)" ::: "memory");
    __builtin_amdgcn_s_barrier();
  }
#undef STAGE
  // epilogue
  int cl = l & 15, rq = (l >> 4) * 4;
#pragma unroll
  for (int n = 0; n < 4; ++n) {
    int nn = n0 + wn * 64 + n * 16 + cl;
    float bnv = bias[nn];
#pragma unroll
    for (int m = 0; m < 8; ++m) {
      int mm = m0 + wm * 128 + m * 16 + rq;
#pragma unroll
      for (int r = 0; r < 4; ++r) {
        float v = acc[m][n][r] + bnv;
        size_t off = (size_t)(mm + r) * N + nn;
        if constexpr (EPI == 1) {
          v = 0.5f * v * (1.f + erff(v * 0.70710678118654752f));
          ((u16*)Cout)[off] = f2bf(v);
        } else if constexpr (EPI == 2) {
          ((float*)Cout)[off] = res[off] + v;
        } else {
          ((u16*)Cout)[off] = f2bf(v);
        }
      }
    }
  }
}

// ---------- window attention: one block per (window, head) ----------
// qkv: [T][1536] bf16 (q|k|v, each head h at h*32). out: [T][512] bf16.
__global__ __launch_bounds__(256) void attn_kernel(const u16* __restrict__ qkv,
                                                   const float* __restrict__ bias_t,
                                                   u16* __restrict__ attn_out) {
  __shared__ __align__(16) u16 vT[32][160];       // v transposed, K padded to 160
  __shared__ __align__(16) u16 Plds[4][16][160];  // per-wave P strip
  __shared__ u32 tok[144];
  int tid = threadIdx.x, lane = tid & 63, wid = tid >> 6;
  int blk = blockIdx.x;
  int h = blk & 15, w = blk >> 4;
  int zi = w >> 6, hi = (w >> 3) & 7, wi = w & 7;

  if (tid < 144) {
    int a = tid / 72, rem = tid - a * 72;
    int b = rem / 12, c = rem - b * 12;
    tok[tid] = ((u32)(zi * 2 + a) * 48 + hi * 6 + b) * 96 + wi * 12 + c;
  }
  for (int e = tid; e < 512; e += 256) vT[e >> 4][144 + (e & 15)] = 0;  // zero K-pad
  __syncthreads();  // tok ready

  // stage V transposed: [d][n]
  for (int idx = tid; idx < 576; idx += 256) {
    int n = idx >> 2, d8 = (idx & 3) * 8;
    u16x8 v = *(const u16x8*)(qkv + (size_t)tok[n] * 1536 + 1024 + h * 32 + d8);
#pragma unroll
    for (int j = 0; j < 8; ++j) vT[d8 + j][n] = v[j];
  }
  // zero this wave's P pad columns (144..159)
#pragma unroll
  for (int rr = 0; rr < 4; ++rr) Plds[wid][(lane >> 4) * 4 + rr][144 + (lane & 15)] = 0;
  __syncthreads();  // vT ready

  const float scale = 0.17677669529663687f;  // 1/sqrt(32)
  for (int rt = wid; rt < 9; rt += 4) {
    int qrow = rt * 16 + (lane & 15);
    i32x4 aq = *(const i32x4*)(qkv + (size_t)tok[qrow] * 1536 + h * 32 + (lane >> 4) * 8);
    f32x4 s[9];
#pragma unroll
    for (int ct = 0; ct < 9; ++ct) {
      int krow = ct * 16 + (lane & 15);
      i32x4 bk = *(const i32x4*)(qkv + (size_t)tok[krow] * 1536 + 512 + h * 32 + (lane >> 4) * 8);
      f32x4 z = {0.f, 0.f, 0.f, 0.f};
      s[ct] = mfma16(aq, bk, z);
    }
    int rowb = rt * 16 + (lane >> 4) * 4;
#pragma unroll
    for (int ct = 0; ct < 9; ++ct)
#pragma unroll
      for (int rr = 0; rr < 4; ++rr)
        s[ct][rr] = s[ct][rr] * scale +
                    bias_t[((size_t)h * 144 + rowb + rr) * 144 + ct * 16 + (lane & 15)];
    float mx[4], sm[4], inv[4];
#pragma unroll
    for (int rr = 0; rr < 4; ++rr) {
      float m = s[0][rr];
#pragma unroll
      for (int ct = 1; ct < 9; ++ct) m = fmaxf(m, s[ct][rr]);
#pragma unroll
      for (int msk = 8; msk >= 1; msk >>= 1) m = fmaxf(m, __shfl_xor(m, msk));
      mx[rr] = m;
      sm[rr] = 0.f;
    }
#pragma unroll
    for (int ct = 0; ct < 9; ++ct)
#pragma unroll
      for (int rr = 0; rr < 4; ++rr) {
        float p = __expf(s[ct][rr] - mx[rr]);
        s[ct][rr] = p;
        sm[rr] += p;
      }
#pragma unroll
    for (int rr = 0; rr < 4; ++rr) {
#pragma unroll
      for (int msk = 8; msk >= 1; msk >>= 1) sm[rr] += __shfl_xor(sm[rr], msk);
      inv[rr] = 1.f / sm[rr];
    }
#pragma unroll
    for (int ct = 0; ct < 9; ++ct)
#pragma unroll
      for (int rr = 0; rr < 4; ++rr)
        Plds[wid][(lane >> 4) * 4 + rr][ct * 16 + (lane & 15)] = f2bf(s[ct][rr] * inv[rr]);
    // PV: O(16x32) = P(16x160) x v(160x32)
#pragma unroll
    for (int dt = 0; dt < 2; ++dt) {
      f32x4 o = {0.f, 0.f, 0.f, 0.f};
#pragma unroll
      for (int ct = 0; ct < 5; ++ct) {
        i32x4 ap = *(const i32x4*)&Plds[wid][lane & 15][ct * 32 + (lane >> 4) * 8];
        i32x4 bv = *(const i32x4*)&vT[dt * 16 + (lane & 15)][ct * 32 + (lane >> 4) * 8];
        o = mfma16(ap, bv, o);
      }
#pragma unroll
      for (int rr = 0; rr < 4; ++rr)
        attn_out[(size_t)tok[rowb + rr] * 512 + h * 32 + dt * 16 + (lane & 15)] = f2bf(o[rr]);
    }
  }
}

// ---------- launch ----------
extern "C" void kernel_launch(void* const* d_in, const int* in_sizes, int n_in,
                              void* d_out, int out_size, void* d_ws, size_t ws_size,
                              hipStream_t stream) {
  const float* x      = (const float*)d_in[0];
  const float* ln1_w  = (const float*)d_in[1];
  const float* ln1_b  = (const float*)d_in[2];
  const float* qkv_w  = (const float*)d_in[3];
  const float* qkv_b  = (const float*)d_in[4];
  const float* rpb    = (const float*)d_in[5];
  const float* proj_w = (const float*)d_in[6];
  const float* proj_b = (const float*)d_in[7];
  const float* ln2_w  = (const float*)d_in[8];
  const float* ln2_b  = (const float*)d_in[9];
  const float* fc1_w  = (const float*)d_in[10];
  const float* fc1_b  = (const float*)d_in[11];
  const float* fc2_w  = (const float*)d_in[12];
  const float* fc2_b  = (const float*)d_in[13];
  const int*   rp_idx = (const int*)d_in[14];
  float* out = (float*)d_out;
  char* ws = (char*)d_ws;

  const int T = 36864;  // 8*48*96 tokens
  // workspace layout (bytes)
  u16*   w_qkv  = (u16*)(ws + 0);                    // 1536*512*2   = 1572864
  u16*   w_proj = (u16*)(ws + 1572864);              // 512*512*2    = 524288
  u16*   w_fc1  = (u16*)(ws + 2097152);              // 2048*512*2   = 2097152
  u16*   w_fc2  = (u16*)(ws + 4194304);              // 512*2048*2   = 2097152
  float* bias_t = (float*)(ws + 6291456);            // 16*144*144*4 = 1327104
  u16*   buf_ln  = (u16*)(ws + 7618560);             // T*512*2      = 37748736
  u16*   buf_qkv = (u16*)(ws + 45367296);            // T*2048*2     = 150994944 (qkv then h)
  u16*   buf_attn= (u16*)(ws + 196362240);           // T*512*2      = 37748736
  // total 234110976 bytes

  // weights -> bf16
  cvt_bf16_kernel<<<3072, 256, 0, stream>>>(qkv_w, w_qkv, 1536 * 512);
  cvt_bf16_kernel<<<1024, 256, 0, stream>>>(proj_w, w_proj, 512 * 512);
  cvt_bf16_kernel<<<4096, 256, 0, stream>>>(fc1_w, w_fc1, 2048 * 512);
  cvt_bf16_kernel<<<4096, 256, 0, stream>>>(fc2_w, w_fc2, 512 * 2048);
  bias_table_kernel<<<1296, 256, 0, stream>>>(rpb, rp_idx, bias_t);

  // LN1
  ln_kernel<<<T / 4, 256, 0, stream>>>(x, ln1_w, ln1_b, buf_ln);
  // QKV: [T,1536]  grid 144*6=864
  gemm256<0><<<dim3((T / 256) * 6), 512, 0, stream>>>(
      buf_ln, w_qkv, qkv_b, nullptr, buf_qkv, T, 1536, 512, 6);
  // attention
  attn_kernel<<<256 * 16, 256, 0, stream>>>(buf_qkv, bias_t, buf_attn);
  // proj + residual(x) -> d_out (fp32, holds x1)   grid 144*2=288
  gemm256<2><<<dim3((T / 256) * 2), 512, 0, stream>>>(
      buf_attn, w_proj, proj_b, x, out, T, 512, 512, 2);
  // LN2 on x1
  ln_kernel<<<T / 4, 256, 0, stream>>>(out, ln2_w, ln2_b, buf_ln);
  // FC1 + gelu -> h (bf16, reuse buf_qkv)   grid 144*8=1152
  gemm256<1><<<dim3((T / 256) * 8), 512, 0, stream>>>(
      buf_ln, w_fc1, fc1_b, nullptr, buf_qkv, T, 2048, 512, 8);
  // FC2 + residual(x1) -> d_out   grid 288
  gemm256<2><<<dim3((T / 256) * 2), 512, 0, stream>>>(
      buf_qkv, w_fc2, fc2_b, out, out, T, 512, 2048, 2);
}

// Round 5
// 753.029 us; speedup vs baseline: 1.1285x; 1.0499x over previous
//
#include <hip/hip_runtime.h>
#include <hip/hip_bf16.h>
#include <cstdint>

typedef unsigned short u16;
typedef unsigned int u32;
typedef __attribute__((ext_vector_type(4))) int i32x4;
typedef __attribute__((ext_vector_type(4))) float f32x4;
typedef __attribute__((ext_vector_type(8))) unsigned short u16x8;

// ---------- helpers ----------
__device__ __forceinline__ u16 f2bf(float f) {
  u32 u = __builtin_bit_cast(u32, f);
  u += 0x7FFFu + ((u >> 16) & 1u);          // RNE
  return (u16)(u >> 16);
}

__device__ __forceinline__ f32x4 mfma16(i32x4 a, i32x4 b, f32x4 c) {
  asm("v_mfma_f32_16x16x32_bf16 %0, %1, %2, %0" : "+v"(c) : "v"(a), "v"(b));
  return c;
}

__device__ __forceinline__ void gload_lds16(const void* g, void* l) {
  __builtin_amdgcn_global_load_lds((__attribute__((address_space(1))) void*)g,
                                   (__attribute__((address_space(3))) void*)l,
                                   16, 0, 0);
}

// ---------- fp32 -> bf16 convert ----------
__global__ __launch_bounds__(256) void cvt_bf16_kernel(const float* __restrict__ s,
                                                       u16* __restrict__ d, int n) {
  int i = blockIdx.x * 256 + threadIdx.x;
  if (i < n) d[i] = f2bf(s[i]);
}

// ---------- bias table: bias_t[h][n][m] = rpb[rp_index[n*144+m]][h] ----------
__global__ __launch_bounds__(256) void bias_table_kernel(const float* __restrict__ rpb,
                                                         const int* __restrict__ rp_index,
                                                         float* __restrict__ bias_t) {
  int i = blockIdx.x * 256 + threadIdx.x;     // < 16*144*144 = 331776
  if (i < 331776) {
    int h = i / 20736;
    int r = i - h * 20736;                    // n*144+m
    bias_t[i] = rpb[rp_index[r] * 16 + h];
  }
}

// ---------- LayerNorm over C=512, out bf16; 4 tokens/block, 1 wave/token ----------
__global__ __launch_bounds__(256) void ln_kernel(const float* __restrict__ x,
                                                 const float* __restrict__ w,
                                                 const float* __restrict__ b,
                                                 u16* __restrict__ out) {
  int lane = threadIdx.x & 63;
  size_t token = (size_t)blockIdx.x * 4 + (threadIdx.x >> 6);
  const float* row = x + token * 512;
  float4 v0 = *(const float4*)(row + lane * 8);
  float4 v1 = *(const float4*)(row + lane * 8 + 4);
  float s  = v0.x + v0.y + v0.z + v0.w + v1.x + v1.y + v1.z + v1.w;
  float ss = v0.x*v0.x + v0.y*v0.y + v0.z*v0.z + v0.w*v0.w
           + v1.x*v1.x + v1.y*v1.y + v1.z*v1.z + v1.w*v1.w;
#pragma unroll
  for (int m = 32; m >= 1; m >>= 1) { s += __shfl_xor(s, m); ss += __shfl_xor(ss, m); }
  float mu  = s * (1.f / 512.f);
  float var = ss * (1.f / 512.f) - mu * mu;
  float rstd = rsqrtf(var + 1e-5f);
  float4 w0 = *(const float4*)(w + lane * 8);
  float4 w1 = *(const float4*)(w + lane * 8 + 4);
  float4 b0 = *(const float4*)(b + lane * 8);
  float4 b1 = *(const float4*)(b + lane * 8 + 4);
  u16x8 o;
  o[0] = f2bf((v0.x - mu) * rstd * w0.x + b0.x);
  o[1] = f2bf((v0.y - mu) * rstd * w0.y + b0.y);
  o[2] = f2bf((v0.z - mu) * rstd * w0.z + b0.z);
  o[3] = f2bf((v0.w - mu) * rstd * w0.w + b0.w);
  o[4] = f2bf((v1.x - mu) * rstd * w1.x + b1.x);
  o[5] = f2bf((v1.y - mu) * rstd * w1.y + b1.y);
  o[6] = f2bf((v1.z - mu) * rstd * w1.z + b1.z);
  o[7] = f2bf((v1.w - mu) * rstd * w1.w + b1.w);
  *(u16x8*)(out + token * 512 + lane * 8) = o;
}

// ---------- GEMM 256x256 tile, BK=64, half-tile pipeline, counted vmcnt ----------
// C[M,N] = A[M,K](bf16) * B[N,K]^T(bf16) + bias
// EPI 0: bf16 out; 1: tanh-gelu->bf16; 2: fp32 out = res + acc + bias
// 8 waves (2M x 4N), per-wave 128x64, acc[8][4], BK=64 (2 k-slices per frag).
// LDS: 2 buf x 4 half-tiles (A0,A1,B0,B1; 16KB each) = 128 KB.
// Per tile: stage 3 halves of t+1, MFMA q2,q3 of t-1 (overlaps the in-flight
// loads), vmcnt(6) [3 halves stay in flight -- T4], barrier, READ24, q0,
// stage 4th half, q1, lgkmcnt(0), barrier.  2 barriers / tile, no vmcnt(0)
// until the last tile.
// Swizzle (both sides, rule #21): chunk c (16B) of a half-tile: row=c>>3,
// slot=c&7, global col slot^(row&7); read addr uses same XOR.
template <int EPI>
__global__ __launch_bounds__(512, 2) void gemm8p(const u16* __restrict__ A,
                                                 const u16* __restrict__ B,
                                                 const float* __restrict__ bias,
                                                 const float* __restrict__ res,
                                                 void* __restrict__ Cout,
                                                 int M, int N, int K, int NBN) {
  __shared__ __align__(16) char sm[131072];
  int tid = threadIdx.x, l = tid & 63, wid = tid >> 6;
  int wm = wid >> 2, wn = wid & 3;
  // T1: bijective XCD swizzle (grids are multiples of 8)
  int nwg = gridDim.x, wg = blockIdx.x;
  int swz = (wg & 7) * (nwg >> 3) + (wg >> 3);
  int bm = swz / NBN, bn = swz - bm * NBN;
  int m0 = bm * 256, n0 = bn * 256;
  // staging: chunk c in a half: row=c>>3 (0..127 via two gloads), slot=c&7
  int crow = tid >> 3;                               // 0..63
  int xo = ((tid & 7) ^ (crow & 7)) * 8;             // pre-swizzled global col
  const u16* pA = A + (size_t)(m0 + crow) * K + xo;
  const u16* pB = B + (size_t)(n0 + crow) * K + xo;
  size_t K64 = (size_t)K * 64, K128 = K64 * 2;
  int ldsS = tid * 16;
  // fragment read offsets
  int l15 = l & 15, l7 = l & 7;
  int s0 = (((l >> 4)) ^ l7) * 16;                   // ks=0 slot byte
  int s1 = (((l >> 4) + 4) ^ l7) * 16;               // ks=1
  int aoff = wm * 16384 + l15 * 128;                 // + m*2048 + s
  int boff = 32768 + (wn >> 1) * 16384 + ((wn & 1) * 64 + l15) * 128;
  f32x4 acc[8][4] = {};
  i32x4 ar[8][2], br[4][2];
  int NT = K >> 6;

#define STG(region, p, koff, dbuf) { \
    gload_lds16((p) + (koff), sm + (dbuf) + (region) + ldsS); \
    gload_lds16((p) + K64 + (koff), sm + (dbuf) + (region) + ldsS + 8192); }

#define QUADX(MH, NH) { \
    _Pragma("unroll") for (int mm_ = 0; mm_ < 4; ++mm_) \
    _Pragma("unroll") for (int nn_ = 0; nn_ < 2; ++nn_) { \
      acc[MH + mm_][NH + nn_] = mfma16(ar[MH + mm_][0], br[NH + nn_][0], acc[MH + mm_][NH + nn_]); \
      acc[MH + mm_][NH + nn_] = mfma16(ar[MH + mm_][1], br[NH + nn_][1], acc[MH + mm_][NH + nn_]); \
    } }

  // prologue: all 4 halves of tile 0 into buf 0
  STG(0,     pA,        0, 0);   // A0
  STG(32768, pB,        0, 0);   // B0
  STG(49152, pB + K128, 0, 0);   // B1
  STG(16384, pA + K128, 0, 0);   // A1

  for (int t = 0; t < NT; ++t) {
    int cb = (t & 1) << 16;
    int nb = cb ^ 65536;
    size_t ko = (size_t)(t + 1) << 6;
    bool nxt = (t + 1 < NT);
    if (nxt) STG(0, pA, ko, nb);              // A0 of t+1
    __builtin_amdgcn_s_setprio(1);
    if (t > 0) QUADX(4, 0);                   // q2 of t-1
    __builtin_amdgcn_s_setprio(0);
    if (nxt) STG(32768, pB, ko, nb);          // B0 of t+1
    __builtin_amdgcn_s_setprio(1);
    if (t > 0) QUADX(4, 2);                   // q3 of t-1
    __builtin_amdgcn_s_setprio(0);
    if (nxt) STG(49152, pB + K128, ko, nb);   // B1 of t+1
    if (nxt) asm volatile("s_waitcnt vmcnt(6)" ::: "memory");
    else     asm volatile("s_waitcnt vmcnt(0)" ::: "memory");
    __builtin_amdgcn_s_barrier();
#pragma unroll
    for (int m = 0; m < 8; ++m) {
      ar[m][0] = *(const i32x4*)(sm + cb + aoff + m * 2048 + s0);
      ar[m][1] = *(const i32x4*)(sm + cb + aoff + m * 2048 + s1);
    }
#pragma unroll
    for (int n = 0; n < 4; ++n) {
      br[n][0] = *(const i32x4*)(sm + cb + boff + n * 2048 + s0);
      br[n][1] = *(const i32x4*)(sm + cb + boff + n * 2048 + s1);
    }
    __builtin_amdgcn_s_setprio(1);
    QUADX(0, 0);                              // q0 of t
    __builtin_amdgcn_s_setprio(0);
    if (nxt) STG(16384, pA + K128, ko, nb);   // A1 of t+1
    __builtin_amdgcn_s_setprio(1);
    QUADX(0, 2);                              // q1 of t
    __builtin_amdgcn_s_setprio(0);
    asm volatile("s_waitcnt lgkmcnt(0)" ::: "memory");
    __builtin_amdgcn_s_barrier();
  }
  QUADX(4, 0);                                // q2, q3 of last tile
  QUADX(4, 2);
#undef STG
#undef QUADX

  // ---------- epilogue ----------
  int cl = l15, rq = (l >> 4) * 4;
  float bnv[4];
#pragma unroll
  for (int n = 0; n < 4; ++n) bnv[n] = bias[n0 + wn * 64 + n * 16 + cl];

  if constexpr (EPI == 2) {
#pragma unroll
    for (int n = 0; n < 4; ++n) {
      int nn = n0 + wn * 64 + n * 16 + cl;
#pragma unroll
      for (int m = 0; m < 8; ++m) {
        int mm = m0 + wm * 128 + m * 16 + rq;
#pragma unroll
        for (int r = 0; r < 4; ++r) {
          size_t off = (size_t)(mm + r) * N + nn;
          ((float*)Cout)[off] = res[off] + acc[m][n][r] + bnv[n];
        }
      }
    }
  } else {
    // LDS-staged vectorized bf16 store: per-wave [32][72] u16 region (144B rows)
    u16* reg = (u16*)(sm + wid * 4608);
#pragma unroll
    for (int p = 0; p < 4; ++p) {
#pragma unroll
      for (int mm = 0; mm < 2; ++mm)
#pragma unroll
        for (int n = 0; n < 4; ++n)
#pragma unroll
          for (int r = 0; r < 4; ++r) {
            float v = acc[p * 2 + mm][n][r] + bnv[n];
            if constexpr (EPI == 1) {
              float u = v * (0.7978845608f + 0.035677408137f * v * v);
              float e = __builtin_amdgcn_exp2f(u * -2.8853900817779268f);
              v = v * __builtin_amdgcn_rcpf(1.f + e);
            }
            reg[(mm * 16 + rq + r) * 72 + n * 16 + cl] = f2bf(v);
          }
#pragma unroll
      for (int k = 0; k < 4; ++k) {
        int c = l + k * 64;
        int row = c >> 3, sub = c & 7;
        i32x4 dv = *(const i32x4*)((const char*)reg + row * 144 + sub * 16);
        size_t grow = (size_t)(m0 + wm * 128 + p * 32 + row);
        *(i32x4*)((u16*)Cout + grow * N + n0 + wn * 64 + sub * 8) = dv;
      }
    }
  }
}

// ---------- window attention: one block per (window, head) ----------
__global__ __launch_bounds__(256) void attn_kernel(const u16* __restrict__ qkv,
                                                   const float* __restrict__ bias_t,
                                                   u16* __restrict__ attn_out) {
  __shared__ __align__(16) u16 vT[32][160];       // v transposed, K padded to 160
  __shared__ __align__(16) u16 Plds[4][16][160];  // per-wave P strip
  __shared__ u32 tok[144];
  int tid = threadIdx.x, lane = tid & 63, wid = tid >> 6;
  int blk = blockIdx.x;
  int h = blk & 15, w = blk >> 4;
  int zi = w >> 6, hi = (w >> 3) & 7, wi = w & 7;

  if (tid < 144) {
    int a = tid / 72, rem = tid - a * 72;
    int b = rem / 12, c = rem - b * 12;
    tok[tid] = ((u32)(zi * 2 + a) * 48 + hi * 6 + b) * 96 + wi * 12 + c;
  }
  for (int e = tid; e < 512; e += 256) vT[e >> 4][144 + (e & 15)] = 0;  // zero K-pad
  __syncthreads();  // tok ready

  for (int idx = tid; idx < 576; idx += 256) {
    int n = idx >> 2, d8 = (idx & 3) * 8;
    u16x8 v = *(const u16x8*)(qkv + (size_t)tok[n] * 1536 + 1024 + h * 32 + d8);
#pragma unroll
    for (int j = 0; j < 8; ++j) vT[d8 + j][n] = v[j];
  }
#pragma unroll
  for (int rr = 0; rr < 4; ++rr) Plds[wid][(lane >> 4) * 4 + rr][144 + (lane & 15)] = 0;
  __syncthreads();  // vT ready

  const float scale = 0.17677669529663687f;  // 1/sqrt(32)
  for (int rt = wid; rt < 9; rt += 4) {
    int qrow = rt * 16 + (lane & 15);
    i32x4 aq = *(const i32x4*)(qkv + (size_t)tok[qrow] * 1536 + h * 32 + (lane >> 4) * 8);
    f32x4 s[9];
#pragma unroll
    for (int ct = 0; ct < 9; ++ct) {
      int krow = ct * 16 + (lane & 15);
      i32x4 bk = *(const i32x4*)(qkv + (size_t)tok[krow] * 1536 + 512 + h * 32 + (lane >> 4) * 8);
      f32x4 z = {0.f, 0.f, 0.f, 0.f};
      s[ct] = mfma16(aq, bk, z);
    }
    int rowb = rt * 16 + (lane >> 4) * 4;
#pragma unroll
    for (int ct = 0; ct < 9; ++ct)
#pragma unroll
      for (int rr = 0; rr < 4; ++rr)
        s[ct][rr] = s[ct][rr] * scale +
                    bias_t[((size_t)h * 144 + rowb + rr) * 144 + ct * 16 + (lane & 15)];
    float mx[4], smm[4], inv[4];
#pragma unroll
    for (int rr = 0; rr < 4; ++rr) {
      float m = s[0][rr];
#pragma unroll
      for (int ct = 1; ct < 9; ++ct) m = fmaxf(m, s[ct][rr]);
#pragma unroll
      for (int msk = 8; msk >= 1; msk >>= 1) m = fmaxf(m, __shfl_xor(m, msk));
      mx[rr] = m;
      smm[rr] = 0.f;
    }
#pragma unroll
    for (int ct = 0; ct < 9; ++ct)
#pragma unroll
      for (int rr = 0; rr < 4; ++rr) {
        float p = __expf(s[ct][rr] - mx[rr]);
        s[ct][rr] = p;
        smm[rr] += p;
      }
#pragma unroll
    for (int rr = 0; rr < 4; ++rr) {
#pragma unroll
      for (int msk = 8; msk >= 1; msk >>= 1) smm[rr] += __shfl_xor(smm[rr], msk);
      inv[rr] = 1.f / smm[rr];
    }
#pragma unroll
    for (int ct = 0; ct < 9; ++ct)
#pragma unroll
      for (int rr = 0; rr < 4; ++rr)
        Plds[wid][(lane >> 4) * 4 + rr][ct * 16 + (lane & 15)] = f2bf(s[ct][rr] * inv[rr]);
#pragma unroll
    for (int dt = 0; dt < 2; ++dt) {
      f32x4 o = {0.f, 0.f, 0.f, 0.f};
#pragma unroll
      for (int ct = 0; ct < 5; ++ct) {
        i32x4 ap = *(const i32x4*)&Plds[wid][lane & 15][ct * 32 + (lane >> 4) * 8];
        i32x4 bv = *(const i32x4*)&vT[dt * 16 + (lane & 15)][ct * 32 + (lane >> 4) * 8];
        o = mfma16(ap, bv, o);
      }
#pragma unroll
      for (int rr = 0; rr < 4; ++rr)
        attn_out[(size_t)tok[rowb + rr] * 512 + h * 32 + dt * 16 + (lane & 15)] = f2bf(o[rr]);
    }
  }
}

// ---------- launch ----------
extern "C" void kernel_launch(void* const* d_in, const int* in_sizes, int n_in,
                              void* d_out, int out_size, void* d_ws, size_t ws_size,
                              hipStream_t stream) {
  const float* x      = (const float*)d_in[0];
  const float* ln1_w  = (const float*)d_in[1];
  const float* ln1_b  = (const float*)d_in[2];
  const float* qkv_w  = (const float*)d_in[3];
  const float* qkv_b  = (const float*)d_in[4];
  const float* rpb    = (const float*)d_in[5];
  const float* proj_w = (const float*)d_in[6];
  const float* proj_b = (const float*)d_in[7];
  const float* ln2_w  = (const float*)d_in[8];
  const float* ln2_b  = (const float*)d_in[9];
  const float* fc1_w  = (const float*)d_in[10];
  const float* fc1_b  = (const float*)d_in[11];
  const float* fc2_w  = (const float*)d_in[12];
  const float* fc2_b  = (const float*)d_in[13];
  const int*   rp_idx = (const int*)d_in[14];
  float* out = (float*)d_out;
  char* ws = (char*)d_ws;

  const int T = 36864;  // 8*48*96 tokens
  u16*   w_qkv  = (u16*)(ws + 0);                    // 1536*512*2
  u16*   w_proj = (u16*)(ws + 1572864);              // 512*512*2
  u16*   w_fc1  = (u16*)(ws + 2097152);              // 2048*512*2
  u16*   w_fc2  = (u16*)(ws + 4194304);              // 512*2048*2
  float* bias_t = (float*)(ws + 6291456);            // 16*144*144*4
  u16*   buf_ln  = (u16*)(ws + 7618560);             // T*512*2
  u16*   buf_qkv = (u16*)(ws + 45367296);            // T*2048*2 (qkv, then h)
  u16*   buf_attn= (u16*)(ws + 196362240);           // T*512*2

  cvt_bf16_kernel<<<3072, 256, 0, stream>>>(qkv_w, w_qkv, 1536 * 512);
  cvt_bf16_kernel<<<1024, 256, 0, stream>>>(proj_w, w_proj, 512 * 512);
  cvt_bf16_kernel<<<4096, 256, 0, stream>>>(fc1_w, w_fc1, 2048 * 512);
  cvt_bf16_kernel<<<4096, 256, 0, stream>>>(fc2_w, w_fc2, 512 * 2048);
  bias_table_kernel<<<1296, 256, 0, stream>>>(rpb, rp_idx, bias_t);

  // LN1
  ln_kernel<<<T / 4, 256, 0, stream>>>(x, ln1_w, ln1_b, buf_ln);
  // QKV: [T,1536]  grid 864
  gemm8p<0><<<dim3((T / 256) * 6), 512, 0, stream>>>(
      buf_ln, w_qkv, qkv_b, nullptr, buf_qkv, T, 1536, 512, 6);
  // attention
  attn_kernel<<<256 * 16, 256, 0, stream>>>(buf_qkv, bias_t, buf_attn);
  // proj + residual(x) -> d_out (fp32 x1)  grid 288
  gemm8p<2><<<dim3((T / 256) * 2), 512, 0, stream>>>(
      buf_attn, w_proj, proj_b, x, out, T, 512, 512, 2);
  // LN2 on x1
  ln_kernel<<<T / 4, 256, 0, stream>>>(out, ln2_w, ln2_b, buf_ln);
  // FC1 + gelu -> h (bf16)  grid 1152
  gemm8p<1><<<dim3((T / 256) * 8), 512, 0, stream>>>(
      buf_ln, w_fc1, fc1_b, nullptr, buf_qkv, T, 2048, 512, 8);
  // FC2 + residual(x1) -> d_out  grid 288
  gemm8p<2><<<dim3((T / 256) * 2), 512, 0, stream>>>(
      buf_qkv, w_fc2, fc2_b, out, out, T, 512, 2048, 2);
}

// Round 8
// 711.319 us; speedup vs baseline: 1.1947x; 1.0586x over previous
//
#include <hip/hip_runtime.h>
#include <hip/hip_bf16.h>
#include <cstdint>

typedef unsigned short u16;
typedef unsigned int u32;
typedef __attribute__((ext_vector_type(4))) int i32x4;
typedef __attribute__((ext_vector_type(4))) float f32x4;
typedef __attribute__((ext_vector_type(8))) unsigned short u16x8;

// ---------- helpers ----------
__device__ __forceinline__ u16 f2bf(float f) {
  u32 u = __builtin_bit_cast(u32, f);
  u += 0x7FFFu + ((u >> 16) & 1u);          // RNE
  return (u16)(u >> 16);
}

__device__ __forceinline__ f32x4 mfma16(i32x4 a, i32x4 b, f32x4 c) {
  asm("v_mfma_f32_16x16x32_bf16 %0, %1, %2, %0" : "+v"(c) : "v"(a), "v"(b));
  return c;
}

__device__ __forceinline__ void gload_lds16(const void* g, void* l) {
  __builtin_amdgcn_global_load_lds((__attribute__((address_space(1))) void*)g,
                                   (__attribute__((address_space(3))) void*)l,
                                   16, 0, 0);
}

// ---------- fp32 -> bf16 convert ----------
__global__ __launch_bounds__(256) void cvt_bf16_kernel(const float* __restrict__ s,
                                                       u16* __restrict__ d, int n) {
  int i = blockIdx.x * 256 + threadIdx.x;
  if (i < n) d[i] = f2bf(s[i]);
}

// ---------- bias table: bias_t[h][n][m] = rpb[rp_index[n*144+m]][h] ----------
__global__ __launch_bounds__(256) void bias_table_kernel(const float* __restrict__ rpb,
                                                         const int* __restrict__ rp_index,
                                                         float* __restrict__ bias_t) {
  int i = blockIdx.x * 256 + threadIdx.x;     // < 16*144*144 = 331776
  if (i < 331776) {
    int h = i / 20736;
    int r = i - h * 20736;                    // n*144+m
    bias_t[i] = rpb[rp_index[r] * 16 + h];
  }
}

// ---------- LayerNorm over C=512, out bf16; 4 tokens/block, 1 wave/token ----------
__global__ __launch_bounds__(256) void ln_kernel(const float* __restrict__ x,
                                                 const float* __restrict__ w,
                                                 const float* __restrict__ b,
                                                 u16* __restrict__ out) {
  int lane = threadIdx.x & 63;
  size_t token = (size_t)blockIdx.x * 4 + (threadIdx.x >> 6);
  const float* row = x + token * 512;
  float4 v0 = *(const float4*)(row + lane * 8);
  float4 v1 = *(const float4*)(row + lane * 8 + 4);
  float s  = v0.x + v0.y + v0.z + v0.w + v1.x + v1.y + v1.z + v1.w;
  float ss = v0.x*v0.x + v0.y*v0.y + v0.z*v0.z + v0.w*v0.w
           + v1.x*v1.x + v1.y*v1.y + v1.z*v1.z + v1.w*v1.w;
#pragma unroll
  for (int m = 32; m >= 1; m >>= 1) { s += __shfl_xor(s, m); ss += __shfl_xor(ss, m); }
  float mu  = s * (1.f / 512.f);
  float var = ss * (1.f / 512.f) - mu * mu;
  float rstd = rsqrtf(var + 1e-5f);
  float4 w0 = *(const float4*)(w + lane * 8);
  float4 w1 = *(const float4*)(w + lane * 8 + 4);
  float4 b0 = *(const float4*)(b + lane * 8);
  float4 b1 = *(const float4*)(b + lane * 8 + 4);
  u16x8 o;
  o[0] = f2bf((v0.x - mu) * rstd * w0.x + b0.x);
  o[1] = f2bf((v0.y - mu) * rstd * w0.y + b0.y);
  o[2] = f2bf((v0.z - mu) * rstd * w0.z + b0.z);
  o[3] = f2bf((v0.w - mu) * rstd * w0.w + b0.w);
  o[4] = f2bf((v1.x - mu) * rstd * w1.x + b1.x);
  o[5] = f2bf((v1.y - mu) * rstd * w1.y + b1.y);
  o[6] = f2bf((v1.z - mu) * rstd * w1.z + b1.z);
  o[7] = f2bf((v1.w - mu) * rstd * w1.w + b1.w);
  *(u16x8*)(out + token * 512 + lane * 8) = o;
}

// ---------- GEMM 128x128 tile, BK=32, 2-deep LDS, counted vmcnt ----------
// C[M,N] = A[M,K](bf16) * B[N,K]^T(bf16) + bias
// EPI 0: bf16 out; 1: tanh-gelu->bf16; 2: fp32 out = res + acc + bias
// m97 geometry (measured 874-912 TF) + counted-vmcnt double buffer:
// 4 waves (2x2), wave tile 64x64 (acc[4][4]); LDS 2 x (A 8KB + B 8KB) = 32KB
// -> with __launch_bounds__(256,3): 3 blocks/CU, 12 waves/CU of TLP.
// Per iter: STAGE(t+1 -> buf^1) 4 gloads; vmcnt(4) [t's 4 landed, t+1's 4
// stay in flight across the barrier -- T4]; barrier; 8 ds_read_b128;
// 16 MFMA; lgkmcnt(0); barrier.
// Swizzle (R4-verified, 0 conflicts): 16B-slot ^= (row>>1)&3 on both the
// global stage source and the ds_read address (rule #21).
template <int EPI>
__global__ __launch_bounds__(256, 3) void gemm128(const u16* __restrict__ A,
                                                  const u16* __restrict__ B,
                                                  const float* __restrict__ bias,
                                                  const float* __restrict__ res,
                                                  void* __restrict__ Cout,
                                                  int M, int N, int K, int NBN) {
  __shared__ __align__(16) char sm[32768];
  int tid = threadIdx.x, l = tid & 63, wid = tid >> 6;
  int wm = wid >> 1, wn = wid & 1;
  // T1: bijective XCD swizzle (grids are multiples of 8)
  int nwg = gridDim.x, wg = blockIdx.x;
  int swz = (wg & 7) * (nwg >> 3) + (wg >> 3);
  int bm = swz / NBN, bn = swz - bm * NBN;
  int m0 = bm * 128, n0 = bn * 128;
  // staging: chunk c=tid: row=tid>>2 (0..63; +64 on 2nd gload), slot=tid&3
  int srow = tid >> 2;
  int xo = ((tid & 3) ^ ((tid >> 3) & 3)) * 8;    // slot ^ (row>>1)&3, elems
  const u16* pA = A + (size_t)(m0 + srow) * K + xo;
  const u16* pB = B + (size_t)(n0 + srow) * K + xo;
  size_t K64 = (size_t)K * 64;
  // fragment read offsets: row r, k-slot (l>>4) ^ ((r>>1)&3) = ^ (l>>1)&3
  int l15 = l & 15;
  int sr = (((l >> 4)) ^ ((l >> 1) & 3)) * 16;
  int aoff = (wm * 64 + l15) * 64 + sr;            // + i*1024
  int boff = 8192 + (wn * 64 + l15) * 64 + sr;     // + j*1024
  f32x4 acc[4][4] = {};
  int NT = K >> 5;

#define STG(t_, dbuf) { \
    const u16* ga = pA + (size_t)(t_) * 32; \
    const u16* gb = pB + (size_t)(t_) * 32; \
    char* lb = sm + (dbuf) * 16384 + tid * 16; \
    gload_lds16(ga, lb); \
    gload_lds16(ga + K64, lb + 4096); \
    gload_lds16(gb, lb + 8192); \
    gload_lds16(gb + K64, lb + 12288); }

  STG(0, 0);
  for (int t = 0; t < NT; ++t) {
    int cb = (t & 1) << 14;
    bool nxt = (t + 1 < NT);
    if (nxt) { STG(t + 1, (t + 1) & 1); }
    if (nxt) asm volatile("s_waitcnt vmcnt(4)" ::: "memory");
    else     asm volatile("s_waitcnt vmcnt(0)" ::: "memory");
    __builtin_amdgcn_s_barrier();
    i32x4 af[4], bf[4];
#pragma unroll
    for (int i = 0; i < 4; ++i) af[i] = *(const i32x4*)(sm + cb + aoff + i * 1024);
#pragma unroll
    for (int j = 0; j < 4; ++j) bf[j] = *(const i32x4*)(sm + cb + boff + j * 1024);
    __builtin_amdgcn_s_setprio(1);
#pragma unroll
    for (int i = 0; i < 4; ++i)
#pragma unroll
      for (int j = 0; j < 4; ++j) acc[i][j] = mfma16(af[i], bf[j], acc[i][j]);
    __builtin_amdgcn_s_setprio(0);
    asm volatile("s_waitcnt lgkmcnt(0)" ::: "memory");
    __builtin_amdgcn_s_barrier();
  }
#undef STG

  // ---------- epilogue ----------
  int cl = l15, rq = (l >> 4) * 4;
  float bnv[4];
#pragma unroll
  for (int j = 0; j < 4; ++j) bnv[j] = bias[n0 + wn * 64 + j * 16 + cl];

  if constexpr (EPI == 2) {
#pragma unroll
    for (int j = 0; j < 4; ++j) {
      int nn = n0 + wn * 64 + j * 16 + cl;
#pragma unroll
      for (int i = 0; i < 4; ++i) {
        int mm = m0 + wm * 64 + i * 16 + rq;
#pragma unroll
        for (int r = 0; r < 4; ++r) {
          size_t off = (size_t)(mm + r) * N + nn;
          ((float*)Cout)[off] = res[off] + acc[i][j][r] + bnv[j];
        }
      }
    }
  } else {
    // LDS-staged vectorized bf16 store: per-wave [16][72] u16 (144B rows)
    u16* reg = (u16*)(sm + wid * 4608);
#pragma unroll
    for (int i = 0; i < 4; ++i) {              // 16-row chunk
#pragma unroll
      for (int j = 0; j < 4; ++j)
#pragma unroll
        for (int r = 0; r < 4; ++r) {
          float v = acc[i][j][r] + bnv[j];
          if constexpr (EPI == 1) {
            float u = v * (0.7978845608f + 0.035677408137f * v * v);
            float e = __builtin_amdgcn_exp2f(u * -2.8853900817779268f);
            v = v * __builtin_amdgcn_rcpf(1.f + e);
          }
          reg[(rq + r) * 72 + j * 16 + cl] = f2bf(v);
        }
#pragma unroll
      for (int k = 0; k < 2; ++k) {
        int c = l + k * 64;                    // 128 chunks of 16B
        int row = c >> 3, sub = c & 7;
        i32x4 dv = *(const i32x4*)((const char*)reg + row * 144 + sub * 16);
        size_t grow = (size_t)(m0 + wm * 64 + i * 16 + row);
        *(i32x4*)((u16*)Cout + grow * N + n0 + wn * 64 + sub * 8) = dv;
      }
    }
  }
}

// ---------- window attention: one block per (window, head) ----------
__global__ __launch_bounds__(256) void attn_kernel(const u16* __restrict__ qkv,
                                                   const float* __restrict__ bias_t,
                                                   u16* __restrict__ attn_out) {
  __shared__ __align__(16) u16 vT[32][160];       // v transposed, K padded to 160
  __shared__ __align__(16) u16 Plds[4][16][160];  // per-wave P strip
  __shared__ u32 tok[144];
  int tid = threadIdx.x, lane = tid & 63, wid = tid >> 6;
  int blk = blockIdx.x;
  int h = blk & 15, w = blk >> 4;
  int zi = w >> 6, hi = (w >> 3) & 7, wi = w & 7;

  if (tid < 144) {
    int a = tid / 72, rem = tid - a * 72;
    int b = rem / 12, c = rem - b * 12;
    tok[tid] = ((u32)(zi * 2 + a) * 48 + hi * 6 + b) * 96 + wi * 12 + c;
  }
  for (int e = tid; e < 512; e += 256) vT[e >> 4][144 + (e & 15)] = 0;  // zero K-pad
  __syncthreads();  // tok ready

  for (int idx = tid; idx < 576; idx += 256) {
    int n = idx >> 2, d8 = (idx & 3) * 8;
    u16x8 v = *(const u16x8*)(qkv + (size_t)tok[n] * 1536 + 1024 + h * 32 + d8);
#pragma unroll
    for (int j = 0; j < 8; ++j) vT[d8 + j][n] = v[j];
  }
#pragma unroll
  for (int rr = 0; rr < 4; ++rr) Plds[wid][(lane >> 4) * 4 + rr][144 + (lane & 15)] = 0;
  __syncthreads();  // vT ready

  const float scale = 0.17677669529663687f;  // 1/sqrt(32)
  for (int rt = wid; rt < 9; rt += 4) {
    int qrow = rt * 16 + (lane & 15);
    i32x4 aq = *(const i32x4*)(qkv + (size_t)tok[qrow] * 1536 + h * 32 + (lane >> 4) * 8);
    f32x4 s[9];
#pragma unroll
    for (int ct = 0; ct < 9; ++ct) {
      int krow = ct * 16 + (lane & 15);
      i32x4 bk = *(const i32x4*)(qkv + (size_t)tok[krow] * 1536 + 512 + h * 32 + (lane >> 4) * 8);
      f32x4 z = {0.f, 0.f, 0.f, 0.f};
      s[ct] = mfma16(aq, bk, z);
    }
    int rowb = rt * 16 + (lane >> 4) * 4;
#pragma unroll
    for (int ct = 0; ct < 9; ++ct)
#pragma unroll
      for (int rr = 0; rr < 4; ++rr)
        s[ct][rr] = s[ct][rr] * scale +
                    bias_t[((size_t)h * 144 + rowb + rr) * 144 + ct * 16 + (lane & 15)];
    float mx[4], smm[4], inv[4];
#pragma unroll
    for (int rr = 0; rr < 4; ++rr) {
      float m = s[0][rr];
#pragma unroll
      for (int ct = 1; ct < 9; ++ct) m = fmaxf(m, s[ct][rr]);
#pragma unroll
      for (int msk = 8; msk >= 1; msk >>= 1) m = fmaxf(m, __shfl_xor(m, msk));
      mx[rr] = m;
      smm[rr] = 0.f;
    }
#pragma unroll
    for (int ct = 0; ct < 9; ++ct)
#pragma unroll
      for (int rr = 0; rr < 4; ++rr) {
        float p = __expf(s[ct][rr] - mx[rr]);
        s[ct][rr] = p;
        smm[rr] += p;
      }
#pragma unroll
    for (int rr = 0; rr < 4; ++rr) {
#pragma unroll
      for (int msk = 8; msk >= 1; msk >>= 1) smm[rr] += __shfl_xor(smm[rr], msk);
      inv[rr] = 1.f / smm[rr];
    }
#pragma unroll
    for (int ct = 0; ct < 9; ++ct)
#pragma unroll
      for (int rr = 0; rr < 4; ++rr)
        Plds[wid][(lane >> 4) * 4 + rr][ct * 16 + (lane & 15)] = f2bf(s[ct][rr] * inv[rr]);
#pragma unroll
    for (int dt = 0; dt < 2; ++dt) {
      f32x4 o = {0.f, 0.f, 0.f, 0.f};
#pragma unroll
      for (int ct = 0; ct < 5; ++ct) {
        i32x4 ap = *(const i32x4*)&Plds[wid][lane & 15][ct * 32 + (lane >> 4) * 8];
        i32x4 bv = *(const i32x4*)&vT[dt * 16 + (lane & 15)][ct * 32 + (lane >> 4) * 8];
        o = mfma16(ap, bv, o);
      }
#pragma unroll
      for (int rr = 0; rr < 4; ++rr)
        attn_out[(size_t)tok[rowb + rr] * 512 + h * 32 + dt * 16 + (lane & 15)] = f2bf(o[rr]);
    }
  }
}

// ---------- launch ----------
extern "C" void kernel_launch(void* const* d_in, const int* in_sizes, int n_in,
                              void* d_out, int out_size, void* d_ws, size_t ws_size,
                              hipStream_t stream) {
  const float* x      = (const float*)d_in[0];
  const float* ln1_w  = (const float*)d_in[1];
  const float* ln1_b  = (const float*)d_in[2];
  const float* qkv_w  = (const float*)d_in[3];
  const float* qkv_b  = (const float*)d_in[4];
  const float* rpb    = (const float*)d_in[5];
  const float* proj_w = (const float*)d_in[6];
  const float* proj_b = (const float*)d_in[7];
  const float* ln2_w  = (const float*)d_in[8];
  const float* ln2_b  = (const float*)d_in[9];
  const float* fc1_w  = (const float*)d_in[10];
  const float* fc1_b  = (const float*)d_in[11];
  const float* fc2_w  = (const float*)d_in[12];
  const float* fc2_b  = (const float*)d_in[13];
  const int*   rp_idx = (const int*)d_in[14];
  float* out = (float*)d_out;
  char* ws = (char*)d_ws;

  const int T = 36864;  // 8*48*96 tokens
  u16*   w_qkv  = (u16*)(ws + 0);                    // 1536*512*2
  u16*   w_proj = (u16*)(ws + 1572864);              // 512*512*2
  u16*   w_fc1  = (u16*)(ws + 2097152);              // 2048*512*2
  u16*   w_fc2  = (u16*)(ws + 4194304);              // 512*2048*2
  float* bias_t = (float*)(ws + 6291456);            // 16*144*144*4
  u16*   buf_ln  = (u16*)(ws + 7618560);             // T*512*2
  u16*   buf_qkv = (u16*)(ws + 45367296);            // T*2048*2 (qkv, then h)
  u16*   buf_attn= (u16*)(ws + 196362240);           // T*512*2

  cvt_bf16_kernel<<<3072, 256, 0, stream>>>(qkv_w, w_qkv, 1536 * 512);
  cvt_bf16_kernel<<<1024, 256, 0, stream>>>(proj_w, w_proj, 512 * 512);
  cvt_bf16_kernel<<<4096, 256, 0, stream>>>(fc1_w, w_fc1, 2048 * 512);
  cvt_bf16_kernel<<<4096, 256, 0, stream>>>(fc2_w, w_fc2, 512 * 2048);
  bias_table_kernel<<<1296, 256, 0, stream>>>(rpb, rp_idx, bias_t);

  // LN1
  ln_kernel<<<T / 4, 256, 0, stream>>>(x, ln1_w, ln1_b, buf_ln);
  // QKV: [T,1536]  grid 288*12 = 3456
  gemm128<0><<<dim3((T / 128) * 12), 256, 0, stream>>>(
      buf_ln, w_qkv, qkv_b, nullptr, buf_qkv, T, 1536, 512, 12);
  // attention
  attn_kernel<<<256 * 16, 256, 0, stream>>>(buf_qkv, bias_t, buf_attn);
  // proj + residual(x) -> d_out (fp32 x1)  grid 288*4 = 1152
  gemm128<2><<<dim3((T / 128) * 4), 256, 0, stream>>>(
      buf_attn, w_proj, proj_b, x, out, T, 512, 512, 4);
  // LN2 on x1
  ln_kernel<<<T / 4, 256, 0, stream>>>(out, ln2_w, ln2_b, buf_ln);
  // FC1 + gelu -> h (bf16)  grid 288*16 = 4608
  gemm128<1><<<dim3((T / 128) * 16), 256, 0, stream>>>(
      buf_ln, w_fc1, fc1_b, nullptr, buf_qkv, T, 2048, 512, 16);
  // FC2 + residual(x1) -> d_out  grid 1152
  gemm128<2><<<dim3((T / 128) * 4), 256, 0, stream>>>(
      buf_qkv, w_fc2, fc2_b, out, out, T, 512, 2048, 4);
}

// Round 10
// 628.712 us; speedup vs baseline: 1.3517x; 1.1314x over previous
//
#include <hip/hip_runtime.h>
#include <hip/hip_bf16.h>
#include <cstdint>

typedef unsigned short u16;
typedef unsigned int u32;
typedef __attribute__((ext_vector_type(4))) int i32x4;
typedef __attribute__((ext_vector_type(4))) float f32x4;
typedef __attribute__((ext_vector_type(8))) unsigned short u16x8;

// ---------- helpers ----------
__device__ __forceinline__ u16 f2bf(float f) {
  u32 u = __builtin_bit_cast(u32, f);
  u += 0x7FFFu + ((u >> 16) & 1u);          // RNE
  return (u16)(u >> 16);
}

__device__ __forceinline__ f32x4 mfma16(i32x4 a, i32x4 b, f32x4 c) {
  asm("v_mfma_f32_16x16x32_bf16 %0, %1, %2, %0" : "+v"(c) : "v"(a), "v"(b));
  return c;
}

__device__ __forceinline__ void gload_lds16(const void* g, void* l) {
  __builtin_amdgcn_global_load_lds((__attribute__((address_space(1))) void*)g,
                                   (__attribute__((address_space(3))) void*)l,
                                   16, 0, 0);
}

// ---------- fp32 -> bf16 convert ----------
__global__ __launch_bounds__(256) void cvt_bf16_kernel(const float* __restrict__ s,
                                                       u16* __restrict__ d, int n) {
  int i = blockIdx.x * 256 + threadIdx.x;
  if (i < n) d[i] = f2bf(s[i]);
}

// ---------- bias table: bias_t[h][n][m] = rpb[rp_index[n*144+m]][h] ----------
__global__ __launch_bounds__(256) void bias_table_kernel(const float* __restrict__ rpb,
                                                         const int* __restrict__ rp_index,
                                                         float* __restrict__ bias_t) {
  int i = blockIdx.x * 256 + threadIdx.x;     // < 16*144*144 = 331776
  if (i < 331776) {
    int h = i / 20736;
    int r = i - h * 20736;                    // n*144+m
    bias_t[i] = rpb[rp_index[r] * 16 + h];
  }
}

// ---------- LayerNorm over C=512, out bf16; 4 tokens/block, 1 wave/token ----------
__global__ __launch_bounds__(256) void ln_kernel(const float* __restrict__ x,
                                                 const float* __restrict__ w,
                                                 const float* __restrict__ b,
                                                 u16* __restrict__ out) {
  int lane = threadIdx.x & 63;
  size_t token = (size_t)blockIdx.x * 4 + (threadIdx.x >> 6);
  const float* row = x + token * 512;
  float4 v0 = *(const float4*)(row + lane * 8);
  float4 v1 = *(const float4*)(row + lane * 8 + 4);
  float s  = v0.x + v0.y + v0.z + v0.w + v1.x + v1.y + v1.z + v1.w;
  float ss = v0.x*v0.x + v0.y*v0.y + v0.z*v0.z + v0.w*v0.w
           + v1.x*v1.x + v1.y*v1.y + v1.z*v1.z + v1.w*v1.w;
#pragma unroll
  for (int m = 32; m >= 1; m >>= 1) { s += __shfl_xor(s, m); ss += __shfl_xor(ss, m); }
  float mu  = s * (1.f / 512.f);
  float var = ss * (1.f / 512.f) - mu * mu;
  float rstd = rsqrtf(var + 1e-5f);
  float4 w0 = *(const float4*)(w + lane * 8);
  float4 w1 = *(const float4*)(w + lane * 8 + 4);
  float4 b0 = *(const float4*)(b + lane * 8);
  float4 b1 = *(const float4*)(b + lane * 8 + 4);
  u16x8 o;
  o[0] = f2bf((v0.x - mu) * rstd * w0.x + b0.x);
  o[1] = f2bf((v0.y - mu) * rstd * w0.y + b0.y);
  o[2] = f2bf((v0.z - mu) * rstd * w0.z + b0.z);
  o[3] = f2bf((v0.w - mu) * rstd * w0.w + b0.w);
  o[4] = f2bf((v1.x - mu) * rstd * w1.x + b1.x);
  o[5] = f2bf((v1.y - mu) * rstd * w1.y + b1.y);
  o[6] = f2bf((v1.z - mu) * rstd * w1.z + b1.z);
  o[7] = f2bf((v1.w - mu) * rstd * w1.w + b1.w);
  *(u16x8*)(out + token * 512 + lane * 8) = o;
}

// ---------- GEMM 128x128 tile, BK=32, 3-deep circular LDS, counted vmcnt ----------
// C[M,N] = A[M,K](bf16) * B[N,K]^T(bf16) + bias
// EPI 0: bf16 out; 1: tanh-gelu->bf16; 2: fp32 out = res + acc + bias
// m97 geometry, 4 waves (2x2), wave tile 64x64 (acc[4][4]).
// LDS: 3 bufs x (A 8KB + B 8KB) = 48KB -> still 3 blocks/CU (144 <= 160KB),
// 12 waves/CU. Prefetch depth TWO tiles (covers ~900cyc HBM latency, m126):
// per iter: STAGE(t+2 -> buf (t+2)%3); vmcnt(8) [t's 4 landed, t+1/t+2's 8
// stay in flight across the barrier]; barrier; 8 ds_read_b128; 16 MFMA;
// lgkmcnt(0); barrier.  Tail: vmcnt(4) then vmcnt(0).
// Race-safety: buf (t+2)%3 was last read at iter t-1; those ds_reads are
// ordered before this STAGE by iter t-1's lgkmcnt(0)+barrier.
// Swizzle (R4-verified, 0 conflicts): 16B-slot ^= (row>>1)&3 on both the
// global stage source and the ds_read address (rule #21).
template <int EPI>
__global__ __launch_bounds__(256, 3) void gemm128(const u16* __restrict__ A,
                                                  const u16* __restrict__ B,
                                                  const float* __restrict__ bias,
                                                  const float* __restrict__ res,
                                                  void* __restrict__ Cout,
                                                  int M, int N, int K, int NBN) {
  __shared__ __align__(16) char sm[49152];
  int tid = threadIdx.x, l = tid & 63, wid = tid >> 6;
  int wm = wid >> 1, wn = wid & 1;
  // T1: bijective XCD swizzle (grids are multiples of 8)
  int nwg = gridDim.x, wg = blockIdx.x;
  int swz = (wg & 7) * (nwg >> 3) + (wg >> 3);
  int bm = swz / NBN, bn = swz - bm * NBN;
  int m0 = bm * 128, n0 = bn * 128;
  // staging: chunk c=tid: row=tid>>2 (0..63; +64 on 2nd gload), slot=tid&3
  int srow = tid >> 2;
  int xo = ((tid & 3) ^ ((tid >> 3) & 3)) * 8;    // slot ^ (row>>1)&3, elems
  const u16* pA = A + (size_t)(m0 + srow) * K + xo;
  const u16* pB = B + (size_t)(n0 + srow) * K + xo;
  size_t K64 = (size_t)K * 64;
  // fragment read offsets: row r, k-slot (l>>4) ^ ((r>>1)&3) = ^ (l>>1)&3
  int l15 = l & 15;
  int sr = (((l >> 4)) ^ ((l >> 1) & 3)) * 16;
  int aoff = (wm * 64 + l15) * 64 + sr;            // + i*1024
  int boff = 8192 + (wn * 64 + l15) * 64 + sr;     // + j*1024
  f32x4 acc[4][4] = {};
  int NT = K >> 5;

#define STG(t_, dbuf) { \
    const u16* ga = pA + (size_t)(t_) * 32; \
    const u16* gb = pB + (size_t)(t_) * 32; \
    char* lb = sm + (dbuf) * 16384 + tid * 16; \
    gload_lds16(ga, lb); \
    gload_lds16(ga + K64, lb + 4096); \
    gload_lds16(gb, lb + 8192); \
    gload_lds16(gb + K64, lb + 12288); }

  STG(0, 0);
  STG(1, 1);
  int cur = 0, stg = 2;
  for (int t = 0; t < NT; ++t) {
    if (t + 2 < NT) { STG(t + 2, stg); }
    int ahead = NT - 1 - t;
    if (ahead >= 2)      asm volatile("s_waitcnt vmcnt(8)" ::: "memory");
    else if (ahead == 1) asm volatile("s_waitcnt vmcnt(4)" ::: "memory");
    else                 asm volatile("s_waitcnt vmcnt(0)" ::: "memory");
    __builtin_amdgcn_s_barrier();
    int cb = cur * 16384;
    i32x4 af[4], bf[4];
#pragma unroll
    for (int i = 0; i < 4; ++i) af[i] = *(const i32x4*)(sm + cb + aoff + i * 1024);
#pragma unroll
    for (int j = 0; j < 4; ++j) bf[j] = *(const i32x4*)(sm + cb + boff + j * 1024);
    __builtin_amdgcn_s_setprio(1);
#pragma unroll
    for (int i = 0; i < 4; ++i)
#pragma unroll
      for (int j = 0; j < 4; ++j) acc[i][j] = mfma16(af[i], bf[j], acc[i][j]);
    __builtin_amdgcn_s_setprio(0);
    asm volatile("s_waitcnt lgkmcnt(0)" ::: "memory");
    __builtin_amdgcn_s_barrier();
    cur = (cur == 2) ? 0 : cur + 1;
    stg = (stg == 2) ? 0 : stg + 1;
  }
#undef STG

  // ---------- epilogue ----------
  int cl = l15, rq = (l >> 4) * 4;
  float bnv[4];
#pragma unroll
  for (int j = 0; j < 4; ++j) bnv[j] = bias[n0 + wn * 64 + j * 16 + cl];

  if constexpr (EPI == 2) {
#pragma unroll
    for (int j = 0; j < 4; ++j) {
      int nn = n0 + wn * 64 + j * 16 + cl;
#pragma unroll
      for (int i = 0; i < 4; ++i) {
        int mm = m0 + wm * 64 + i * 16 + rq;
#pragma unroll
        for (int r = 0; r < 4; ++r) {
          size_t off = (size_t)(mm + r) * N + nn;
          ((float*)Cout)[off] = res[off] + acc[i][j][r] + bnv[j];
        }
      }
    }
  } else {
    // LDS-staged vectorized bf16 store: per-wave [16][72] u16 (144B rows)
    u16* reg = (u16*)(sm + wid * 4608);
#pragma unroll
    for (int i = 0; i < 4; ++i) {              // 16-row chunk
#pragma unroll
      for (int j = 0; j < 4; ++j)
#pragma unroll
        for (int r = 0; r < 4; ++r) {
          float v = acc[i][j][r] + bnv[j];
          if constexpr (EPI == 1) {
            float u = v * (0.7978845608f + 0.035677408137f * v * v);
            float e = __builtin_amdgcn_exp2f(u * -2.8853900817779268f);
            v = v * __builtin_amdgcn_rcpf(1.f + e);
          }
          reg[(rq + r) * 72 + j * 16 + cl] = f2bf(v);
        }
#pragma unroll
      for (int k = 0; k < 2; ++k) {
        int c = l + k * 64;                    // 128 chunks of 16B
        int row = c >> 3, sub = c & 7;
        i32x4 dv = *(const i32x4*)((const char*)reg + row * 144 + sub * 16);
        size_t grow = (size_t)(m0 + wm * 64 + i * 16 + row);
        *(i32x4*)((u16*)Cout + grow * N + n0 + wn * 64 + sub * 8) = dv;
      }
    }
  }
}

// ---------- window attention: one block per (window, head) ----------
__global__ __launch_bounds__(256) void attn_kernel(const u16* __restrict__ qkv,
                                                   const float* __restrict__ bias_t,
                                                   u16* __restrict__ attn_out) {
  __shared__ __align__(16) u16 vT[32][160];       // v transposed, K padded to 160
  __shared__ __align__(16) u16 Plds[4][16][160];  // per-wave P strip
  __shared__ u32 tok[144];
  int tid = threadIdx.x, lane = tid & 63, wid = tid >> 6;
  int blk = blockIdx.x;
  int h = blk & 15, w = blk >> 4;
  int zi = w >> 6, hi = (w >> 3) & 7, wi = w & 7;

  if (tid < 144) {
    int a = tid / 72, rem = tid - a * 72;
    int b = rem / 12, c = rem - b * 12;
    tok[tid] = ((u32)(zi * 2 + a) * 48 + hi * 6 + b) * 96 + wi * 12 + c;
  }
  for (int e = tid; e < 512; e += 256) vT[e >> 4][144 + (e & 15)] = 0;  // zero K-pad
  __syncthreads();  // tok ready

  for (int idx = tid; idx < 576; idx += 256) {
    int n = idx >> 2, d8 = (idx & 3) * 8;
    u16x8 v = *(const u16x8*)(qkv + (size_t)tok[n] * 1536 + 1024 + h * 32 + d8);
#pragma unroll
    for (int j = 0; j < 8; ++j) vT[d8 + j][n] = v[j];
  }
#pragma unroll
  for (int rr = 0; rr < 4; ++rr) Plds[wid][(lane >> 4) * 4 + rr][144 + (lane & 15)] = 0;
  __syncthreads();  // vT ready

  const float scale = 0.17677669529663687f;  // 1/sqrt(32)
  for (int rt = wid; rt < 9; rt += 4) {
    int qrow = rt * 16 + (lane & 15);
    i32x4 aq = *(const i32x4*)(qkv + (size_t)tok[qrow] * 1536 + h * 32 + (lane >> 4) * 8);
    f32x4 s[9];
#pragma unroll
    for (int ct = 0; ct < 9; ++ct) {
      int krow = ct * 16 + (lane & 15);
      i32x4 bk = *(const i32x4*)(qkv + (size_t)tok[krow] * 1536 + 512 + h * 32 + (lane >> 4) * 8);
      f32x4 z = {0.f, 0.f, 0.f, 0.f};
      s[ct] = mfma16(aq, bk, z);
    }
    int rowb = rt * 16 + (lane >> 4) * 4;
#pragma unroll
    for (int ct = 0; ct < 9; ++ct)
#pragma unroll
      for (int rr = 0; rr < 4; ++rr)
        s[ct][rr] = s[ct][rr] * scale +
                    bias_t[((size_t)h * 144 + rowb + rr) * 144 + ct * 16 + (lane & 15)];
    float mx[4], smm[4], inv[4];
#pragma unroll
    for (int rr = 0; rr < 4; ++rr) {
      float m = s[0][rr];
#pragma unroll
      for (int ct = 1; ct < 9; ++ct) m = fmaxf(m, s[ct][rr]);
#pragma unroll
      for (int msk = 8; msk >= 1; msk >>= 1) m = fmaxf(m, __shfl_xor(m, msk));
      mx[rr] = m;
      smm[rr] = 0.f;
    }
#pragma unroll
    for (int ct = 0; ct < 9; ++ct)
#pragma unroll
      for (int rr = 0; rr < 4; ++rr) {
        float p = __expf(s[ct][rr] - mx[rr]);
        s[ct][rr] = p;
        smm[rr] += p;
      }
#pragma unroll
    for (int rr = 0; rr < 4; ++rr) {
#pragma unroll
      for (int msk = 8; msk >= 1; msk >>= 1) smm[rr] += __shfl_xor(smm[rr], msk);
      inv[rr] = 1.f / smm[rr];
    }
#pragma unroll
    for (int ct = 0; ct < 9; ++ct)
#pragma unroll
      for (int rr = 0; rr < 4; ++rr)
        Plds[wid][(lane >> 4) * 4 + rr][ct * 16 + (lane & 15)] = f2bf(s[ct][rr] * inv[rr]);
#pragma unroll
    for (int dt = 0; dt < 2; ++dt) {
      f32x4 o = {0.f, 0.f, 0.f, 0.f};
#pragma unroll
      for (int ct = 0; ct < 5; ++ct) {
        i32x4 ap = *(const i32x4*)&Plds[wid][lane & 15][ct * 32 + (lane >> 4) * 8];
        i32x4 bv = *(const i32x4*)&vT[dt * 16 + (lane & 15)][ct * 32 + (lane >> 4) * 8];
        o = mfma16(ap, bv, o);
      }
#pragma unroll
      for (int rr = 0; rr < 4; ++rr)
        attn_out[(size_t)tok[rowb + rr] * 512 + h * 32 + dt * 16 + (lane & 15)] = f2bf(o[rr]);
    }
  }
}

// ---------- launch ----------
extern "C" void kernel_launch(void* const* d_in, const int* in_sizes, int n_in,
                              void* d_out, int out_size, void* d_ws, size_t ws_size,
                              hipStream_t stream) {
  const float* x      = (const float*)d_in[0];
  const float* ln1_w  = (const float*)d_in[1];
  const float* ln1_b  = (const float*)d_in[2];
  const float* qkv_w  = (const float*)d_in[3];
  const float* qkv_b  = (const float*)d_in[4];
  const float* rpb    = (const float*)d_in[5];
  const float* proj_w = (const float*)d_in[6];
  const float* proj_b = (const float*)d_in[7];
  const float* ln2_w  = (const float*)d_in[8];
  const float* ln2_b  = (const float*)d_in[9];
  const float* fc1_w  = (const float*)d_in[10];
  const float* fc1_b  = (const float*)d_in[11];
  const float* fc2_w  = (const float*)d_in[12];
  const float* fc2_b  = (const float*)d_in[13];
  const int*   rp_idx = (const int*)d_in[14];
  float* out = (float*)d_out;
  char* ws = (char*)d_ws;

  const int T = 36864;  // 8*48*96 tokens
  u16*   w_qkv  = (u16*)(ws + 0);                    // 1536*512*2
  u16*   w_proj = (u16*)(ws + 1572864);              // 512*512*2
  u16*   w_fc1  = (u16*)(ws + 2097152);              // 2048*512*2
  u16*   w_fc2  = (u16*)(ws + 4194304);              // 512*2048*2
  float* bias_t = (float*)(ws + 6291456);            // 16*144*144*4
  u16*   buf_ln  = (u16*)(ws + 7618560);             // T*512*2
  u16*   buf_qkv = (u16*)(ws + 45367296);            // T*2048*2 (qkv, then h)
  u16*   buf_attn= (u16*)(ws + 196362240);           // T*512*2

  cvt_bf16_kernel<<<3072, 256, 0, stream>>>(qkv_w, w_qkv, 1536 * 512);
  cvt_bf16_kernel<<<1024, 256, 0, stream>>>(proj_w, w_proj, 512 * 512);
  cvt_bf16_kernel<<<4096, 256, 0, stream>>>(fc1_w, w_fc1, 2048 * 512);
  cvt_bf16_kernel<<<4096, 256, 0, stream>>>(fc2_w, w_fc2, 512 * 2048);
  bias_table_kernel<<<1296, 256, 0, stream>>>(rpb, rp_idx, bias_t);

  // LN1
  ln_kernel<<<T / 4, 256, 0, stream>>>(x, ln1_w, ln1_b, buf_ln);
  // QKV: [T,1536]  grid 288*12 = 3456
  gemm128<0><<<dim3((T / 128) * 12), 256, 0, stream>>>(
      buf_ln, w_qkv, qkv_b, nullptr, buf_qkv, T, 1536, 512, 12);
  // attention
  attn_kernel<<<256 * 16, 256, 0, stream>>>(buf_qkv, bias_t, buf_attn);
  // proj + residual(x) -> d_out (fp32 x1)  grid 288*4 = 1152
  gemm128<2><<<dim3((T / 128) * 4), 256, 0, stream>>>(
      buf_attn, w_proj, proj_b, x, out, T, 512, 512, 4);
  // LN2 on x1
  ln_kernel<<<T / 4, 256, 0, stream>>>(out, ln2_w, ln2_b, buf_ln);
  // FC1 + gelu -> h (bf16)  grid 288*16 = 4608
  gemm128<1><<<dim3((T / 128) * 16), 256, 0, stream>>>(
      buf_ln, w_fc1, fc1_b, nullptr, buf_qkv, T, 2048, 512, 16);
  // FC2 + residual(x1) -> d_out  grid 1152
  gemm128<2><<<dim3((T / 128) * 4), 256, 0, stream>>>(
      buf_qkv, w_fc2, fc2_b, out, out, T, 512, 2048, 4);
}